// Round 5
// baseline (102086.377 us; speedup 1.0000x reference)
//
#include <hip/hip_runtime.h>
#include <math.h>

#define Tn   16384
#define Mg   200
#define Nc   6
#define TOT  1200
#define Kk   25
#define Din  784

// ---------------------------------------------------------------- transpose
__global__ void transpose_k(const float* __restrict__ src, float* __restrict__ dst,
                            int R, int C) {
    __shared__ float tile[32][33];
    int bx = blockIdx.x * 32, by = blockIdx.y * 32;
    int x = bx + threadIdx.x;
    for (int j = 0; j < 32; j += 8) {
        int y = by + threadIdx.y + j;
        if (x < C && y < R) tile[threadIdx.y + j][threadIdx.x] = src[(size_t)y * C + x];
    }
    __syncthreads();
    int x2 = by + threadIdx.x;
    for (int j = 0; j < 32; j += 8) {
        int y2 = bx + threadIdx.y + j;
        if (x2 < R && y2 < C) dst[(size_t)y2 * R + x2] = tile[threadIdx.x][threadIdx.y + j];
    }
}

// ------------------------------------------------- Za = X @ Wa^T + ba  (16384 x 200)
__global__ void za_k(const float* __restrict__ X, const float* __restrict__ Wa,
                     const float* __restrict__ ba, float* __restrict__ Za) {
    __shared__ float xs[16][788];
    const int tid = threadIdx.x;
    const int t0  = blockIdx.x * 16;
    for (int idx = tid; idx < 16 * Din; idx += 256) {
        int tt = idx / Din, kk = idx - tt * Din;
        xs[tt][kk] = X[(size_t)(t0 + tt) * Din + kk];
    }
    __syncthreads();
    const int tq = tid & 15, gq = tid >> 4;
    const float4* xrow = reinterpret_cast<const float4*>(&xs[tq][0]);
    for (int g = gq; g < Mg; g += 16) {
        float acc = ba[g];
        const float4* wrow = reinterpret_cast<const float4*>(Wa + (size_t)g * Din);
        for (int k4 = 0; k4 < Din / 4; ++k4) {
            float4 a = xrow[k4], b = wrow[k4];
            acc = fmaf(a.x, b.x, acc); acc = fmaf(a.y, b.y, acc);
            acc = fmaf(a.z, b.z, acc); acc = fmaf(a.w, b.w, acc);
        }
        Za[(size_t)(t0 + tq) * Mg + g] = acc;
    }
}

// ------------------------------------------------------------- serial recurrence
// 1024 threads = 16 waves = 4 waves/SIMD. Quarter q = tid>>8, g = tid&255.
// Q0 (owners, g<200): u/psi/bb state in registers. Q1-Q3: helpers for group g.
// Rank scan split 4x50 keys; column gather split 4/7/7/7, helper partials in
// LDS uB[3][1200], folded by owners at the start of the next step.
__launch_bounds__(1024, 4)
__global__ void serial_k(const float* __restrict__ Za, const float* __restrict__ WbT,
                         const float* __restrict__ bb,
                         float* __restrict__ Yval, int* __restrict__ Yidx,
                         float* __restrict__ outTail) {
    __shared__ alignas(16) unsigned long long lamk[Mg];
    __shared__ alignas(16) unsigned long long sel[26];
    __shared__ alignas(16) float red[4];
    __shared__ alignas(16) float uB[3][TOT];
    __shared__ int rpart[3][Mg];

    const int tid = threadIdx.x;
    const int q   = tid >> 8;
    const int g   = tid & 255;
    const bool own  = (g < Mg);
    const bool ownA = (q == 0) && own;
    const int b = Nc * g;

    float u0=0.f,u1=0.f,u2=0.f,u3=0.f,u4=0.f,u5=0.f;
    float p0=0.f,p1=0.f,p2=0.f,p3=0.f,p4=0.f,p5=0.f;
    float b0=0.f,b1=0.f,b2=0.f,b3=0.f,b4=0.f,b5=0.f;
    float alpha = 0.f, zb = 0.f;
    if (ownA) {
        b0=bb[b]; b1=bb[b+1]; b2=bb[b+2]; b3=bb[b+3]; b4=bb[b+4]; b5=bb[b+5];
        zb = Za[g];
    }
    for (int i = tid; i < 3 * TOT; i += 1024) (&uB[0][0])[i] = 0.f;
    __syncthreads();

    const float* baseW = WbT + b;

    for (int t = 0; t < Tn; ++t) {
        float zn = 0.f;
        if (ownA && t + 1 < Tn) zn = Za[(size_t)(t + 1) * Mg + g];

        // ---- A (Q0): fold helper partials, sigma, wave-min -> red
        float s0=0,s1=0,s2=0,s3=0,s4=0,s5=0;
        if (q == 0) {
            float lmin = INFINITY;
            if (own) {
                const float2* w0 = reinterpret_cast<const float2*>(&uB[0][b]);
                const float2* w1 = reinterpret_cast<const float2*>(&uB[1][b]);
                const float2* w2 = reinterpret_cast<const float2*>(&uB[2][b]);
                float2 a0=w0[0], a1=w0[1], a2=w0[2];
                float2 d0=w1[0], d1=w1[1], d2=w1[2];
                float2 e0=w2[0], e1=w2[1], e2=w2[2];
                u0 += a0.x + d0.x + e0.x; u1 += a0.y + d0.y + e0.y;
                u2 += a1.x + d1.x + e1.x; u3 += a1.y + d1.y + e1.y;
                u4 += a2.x + d2.x + e2.x; u5 += a2.y + d2.y + e2.y;
                float inv = (alpha == 0.f) ? 1.f : (1.f / alpha);
                s0 = fmaf(u0, inv, b0 + zb); s1 = fmaf(u1, inv, b1 + zb);
                s2 = fmaf(u2, inv, b2 + zb); s3 = fmaf(u3, inv, b3 + zb);
                s4 = fmaf(u4, inv, b4 + zb); s5 = fmaf(u5, inv, b5 + zb);
                lmin = fminf(fminf(fminf(s0,s1),fminf(s2,s3)),fminf(s4,s5));
            }
            for (int o = 32; o; o >>= 1) lmin = fminf(lmin, __shfl_down(lmin, o));
            if ((tid & 63) == 0) red[tid >> 6] = lmin;
        }
        __syncthreads();                                   // bar1

        // ---- B (Q0): global min, pi, argmax, sortable key
        unsigned long long myk = 0ull;
        float sb=0.f, pb=0.f; int bj = 0;
        if (ownA) {
            float4 r4 = *reinterpret_cast<const float4*>(red);
            float m1 = 1.f - fminf(fminf(r4.x, r4.y), fminf(r4.z, r4.w));
            float best = -INFINITY;
            float sa[6] = {s0,s1,s2,s3,s4,s5};
            float pa[6] = {p0,p1,p2,p3,p4,p5};
            #pragma unroll
            for (int j = 0; j < Nc; ++j) {
                float pv = (1.f - pa[j]) * (sa[j] + m1);
                if (pv > best) { best = pv; bj = j; sb = sa[j]; pb = pa[j]; }
            }
            unsigned ub = __float_as_uint(best);
            ub ^= (unsigned)(((int)ub) >> 31) | 0x80000000u;
            myk = ((unsigned long long)ub << 32) | (unsigned long long)(0xFFFFFFFFu - (unsigned)g);
            lamk[g] = myk;
        }
        __syncthreads();                                   // bar2

        // ---- C: 4-way split rank scan; owners overlap tanh
        int rr = 0; float yv = 0.f, dc = 0.f;
        if (own) {
            if (q) myk = lamk[g];
            const ulonglong2* L = reinterpret_cast<const ulonglong2*>(lamk) + 25 * q;
            #pragma unroll
            for (int i = 0; i < 25; ++i) {
                ulonglong2 kv = L[i];
                rr += (kv.x > myk) + (kv.y > myk);
            }
            if (q == 0) {
                float y = tanhf(sb);
                yv = fmaxf(y, 0.f);
                dc = fmaxf(y - 0.5f * pb, 0.f);
            } else {
                rpart[q - 1][g] = rr;
            }
        }
        __syncthreads();                                   // bar3

        // ---- D (Q0): combine ranks, selection, psi update
        if (ownA) {
            int r = rr + rpart[0][g] + rpart[1][g] + rpart[2][g];
            float d = 0.f;
            if (r < Kk) {
                d = dc;
                sel[r] = ((unsigned long long)(unsigned)((b + bj) * TOT) << 32) |
                         (unsigned long long)__float_as_uint(d);
                Yval[(size_t)t * Kk + r] = yv;
                Yidx[(size_t)t * Kk + r] = g;
            }
            p0 = 0.5f*p0 + ((bj==0)?d:0.f); p1 = 0.5f*p1 + ((bj==1)?d:0.f);
            p2 = 0.5f*p2 + ((bj==2)?d:0.f); p3 = 0.5f*p3 + ((bj==3)?d:0.f);
            p4 = 0.5f*p4 + ((bj==4)?d:0.f); p5 = 0.5f*p5 + ((bj==5)?d:0.f);
        }
        __syncthreads();                                   // bar4

        // ---- E: split gather. Q0: cols 0..3 (+alpha). Qq: cols 4+7(q-1)..4+7q-1.
        if (own) {
            const ulonglong2* S = reinterpret_cast<const ulonglong2*>(sel);
            if (q == 0) {
                ulonglong2 sraw[13];
                #pragma unroll
                for (int i = 0; i < 13; ++i) sraw[i] = S[i];
                float asum = 0.f;
                #pragma unroll
                for (int k = 0; k < Kk; ++k) {
                    unsigned long long v = (k & 1) ? sraw[k >> 1].y : sraw[k >> 1].x;
                    asum += __uint_as_float((unsigned)v);
                }
                alpha = 0.5f * alpha + asum;
                float sd[4]; int so[4];
                #pragma unroll
                for (int k = 0; k < 4; ++k) {
                    unsigned long long v = (k & 1) ? sraw[k >> 1].y : sraw[k >> 1].x;
                    sd[k] = __uint_as_float((unsigned)v);
                    so[k] = (int)(v >> 32);
                }
                float2 c0[4], c1[4], c2[4];
                #pragma unroll
                for (int k = 0; k < 4; ++k) {
                    const float* cp = baseW + so[k];
                    c0[k] = *reinterpret_cast<const float2*>(cp);
                    c1[k] = *reinterpret_cast<const float2*>(cp + 2);
                    c2[k] = *reinterpret_cast<const float2*>(cp + 4);
                }
                __builtin_amdgcn_sched_barrier(0);
                float a0=0.5f*u0, a1=0.5f*u1, a2=0.5f*u2, a3=0.5f*u3, a4=0.5f*u4, a5=0.5f*u5;
                #pragma unroll
                for (int k = 0; k < 4; ++k) {
                    float dk = sd[k];
                    a0 = fmaf(dk, c0[k].x, a0); a1 = fmaf(dk, c0[k].y, a1);
                    a2 = fmaf(dk, c1[k].x, a2); a3 = fmaf(dk, c1[k].y, a3);
                    a4 = fmaf(dk, c2[k].x, a4); a5 = fmaf(dk, c2[k].y, a5);
                }
                u0=a0; u1=a1; u2=a2; u3=a3; u4=a4; u5=a5;
                zb = zn;
            } else {
                const int k0 = 4 + 7 * (q - 1);
                const int i0 = k0 >> 1;
                ulonglong2 sraw[4];
                #pragma unroll
                for (int i = 0; i < 4; ++i) sraw[i] = S[i0 + i];
                float sd[7]; int so[7];
                #pragma unroll
                for (int j = 0; j < 7; ++j) {
                    int kk = k0 + j;
                    unsigned long long v = (kk & 1) ? sraw[(kk >> 1) - i0].y
                                                    : sraw[(kk >> 1) - i0].x;
                    sd[j] = __uint_as_float((unsigned)v);
                    so[j] = (int)(v >> 32);
                }
                float2 c0[7], c1[7], c2[7];
                #pragma unroll
                for (int j = 0; j < 7; ++j) {
                    const float* cp = baseW + so[j];
                    c0[j] = *reinterpret_cast<const float2*>(cp);
                    c1[j] = *reinterpret_cast<const float2*>(cp + 2);
                    c2[j] = *reinterpret_cast<const float2*>(cp + 4);
                }
                __builtin_amdgcn_sched_barrier(0);
                float a0=0,a1=0,a2=0,a3=0,a4=0,a5=0;
                #pragma unroll
                for (int j = 0; j < 7; ++j) {
                    float dk = sd[j];
                    a0 = fmaf(dk, c0[j].x, a0); a1 = fmaf(dk, c0[j].y, a1);
                    a2 = fmaf(dk, c1[j].x, a2); a3 = fmaf(dk, c1[j].y, a3);
                    a4 = fmaf(dk, c2[j].x, a4); a5 = fmaf(dk, c2[j].y, a5);
                }
                float2* w = reinterpret_cast<float2*>(&uB[q - 1][b]);
                w[0] = make_float2(a0, a1);
                w[1] = make_float2(a2, a3);
                w[2] = make_float2(a4, a5);
            }
        }
        __syncthreads();                                   // bar5
    }

    // ---- epilogue: x_b, phi, psi
    if (ownA) {
        float inv = (alpha == 0.f) ? 1.f : (1.f / alpha);
        float pa[6] = {p0,p1,p2,p3,p4,p5};
        #pragma unroll
        for (int j = 0; j < Nc; ++j) {
            outTail[b + j]           = pa[j] * inv;
            outTail[TOT + b + j]     = pa[j];
            outTail[2 * TOT + b + j] = pa[j];
        }
    }
}

// ------------------------------------------------- preds = bd + sum val * WdT[idx]
__global__ void preds_k(const float* __restrict__ Yval, const int* __restrict__ Yidx,
                        const float* __restrict__ WdT, const float* __restrict__ bd,
                        float* __restrict__ out) {
    const int t = blockIdx.x;
    __shared__ float sv[Kk];
    __shared__ int   si[Kk];
    if (threadIdx.x < Kk) {
        sv[threadIdx.x] = Yval[(size_t)t * Kk + threadIdx.x];
        si[threadIdx.x] = Yidx[(size_t)t * Kk + threadIdx.x];
    }
    __syncthreads();
    for (int d = threadIdx.x; d < Din; d += 256) {
        float acc = bd[d];
        #pragma unroll
        for (int k = 0; k < Kk; ++k)
            acc = fmaf(sv[k], WdT[(size_t)si[k] * Din + d], acc);
        out[(size_t)t * Din + d] = acc;
    }
}

extern "C" void kernel_launch(void* const* d_in, const int* in_sizes, int n_in,
                              void* d_out, int out_size, void* d_ws, size_t ws_size,
                              hipStream_t stream) {
    const float* X  = (const float*)d_in[0];
    const float* Wa = (const float*)d_in[1];
    const float* ba = (const float*)d_in[2];
    const float* Wb = (const float*)d_in[3];
    const float* bb = (const float*)d_in[4];
    const float* Wd = (const float*)d_in[5];
    const float* bd = (const float*)d_in[6];
    float* out = (float*)d_out;

    float* w    = (float*)d_ws;
    float* Za   = w;                                   // 16384*200
    float* WbT  = Za  + (size_t)Tn * Mg;               // 1200*1200
    float* WdT  = WbT + (size_t)TOT * TOT;             // 200*784
    float* Yv   = WdT + (size_t)Mg * Din;              // 16384*25
    int*   Yi   = (int*)(Yv + (size_t)Tn * Kk);        // 16384*25

    dim3 tb(32, 8);
    transpose_k<<<dim3((TOT + 31) / 32, (TOT + 31) / 32), tb, 0, stream>>>(Wb, WbT, TOT, TOT);
    transpose_k<<<dim3((Mg + 31) / 32, (Din + 31) / 32), tb, 0, stream>>>(Wd, WdT, Din, Mg);
    za_k<<<Tn / 16, 256, 0, stream>>>(X, Wa, ba, Za);
    serial_k<<<1, 1024, 0, stream>>>(Za, WbT, bb, Yv, Yi, out + (size_t)Tn * Din);
    preds_k<<<Tn, 256, 0, stream>>>(Yv, Yi, WdT, bd, out);
}

// Round 6
// 78090.039 us; speedup vs baseline: 1.3073x; 1.3073x over previous
//
#include <hip/hip_runtime.h>
#include <math.h>

#define Tn   16384
#define Mg   200
#define Nc   6
#define TOT  1200
#define Kk   25
#define Din  784
#define CH   32                 // Za/Y chunk length (steps)

// ---------------------------------------------------------------- transpose
__global__ void transpose_k(const float* __restrict__ src, float* __restrict__ dst,
                            int R, int C) {
    __shared__ float tile[32][33];
    int bx = blockIdx.x * 32, by = blockIdx.y * 32;
    int x = bx + threadIdx.x;
    for (int j = 0; j < 32; j += 8) {
        int y = by + threadIdx.y + j;
        if (x < C && y < R) tile[threadIdx.y + j][threadIdx.x] = src[(size_t)y * C + x];
    }
    __syncthreads();
    int x2 = by + threadIdx.x;
    for (int j = 0; j < 32; j += 8) {
        int y2 = bx + threadIdx.y + j;
        if (x2 < R && y2 < C) dst[(size_t)y2 * R + x2] = tile[threadIdx.x][threadIdx.y + j];
    }
}

// ------------------------------------------------- Za = X @ Wa^T + ba  (16384 x 200)
__global__ void za_k(const float* __restrict__ X, const float* __restrict__ Wa,
                     const float* __restrict__ ba, float* __restrict__ Za) {
    __shared__ float xs[16][788];
    const int tid = threadIdx.x;
    const int t0  = blockIdx.x * 16;
    for (int idx = tid; idx < 16 * Din; idx += 256) {
        int tt = idx / Din, kk = idx - tt * Din;
        xs[tt][kk] = X[(size_t)(t0 + tt) * Din + kk];
    }
    __syncthreads();
    const int tq = tid & 15, gq = tid >> 4;
    const float4* xrow = reinterpret_cast<const float4*>(&xs[tq][0]);
    for (int g = gq; g < Mg; g += 16) {
        float acc = ba[g];
        const float4* wrow = reinterpret_cast<const float4*>(Wa + (size_t)g * Din);
        for (int k4 = 0; k4 < Din / 4; ++k4) {
            float4 a = xrow[k4], b = wrow[k4];
            acc = fmaf(a.x, b.x, acc); acc = fmaf(a.y, b.y, acc);
            acc = fmaf(a.z, b.z, acc); acc = fmaf(a.w, b.w, acc);
        }
        Za[(size_t)(t0 + tq) * Mg + g] = acc;
    }
}

// ------------------------------------------------------------- serial recurrence
// 256 threads, 3 barriers/step. Owner thread g<200 keeps u[6], psi[6], bb[6] in
// registers. Za staged in LDS per 32-step chunk; (idx,y) packed u64 buffered in
// LDS and flushed once per chunk -> no per-step global ops inside barrier drains.
__launch_bounds__(256, 1)
__global__ void serial_k(const float* __restrict__ Za, const float* __restrict__ WbT,
                         const float* __restrict__ bb,
                         unsigned long long* __restrict__ YP,
                         float* __restrict__ outTail) {
    __shared__ alignas(16) unsigned long long lamk[Mg];
    __shared__ alignas(16) unsigned long long sel[26];
    __shared__ alignas(16) float red[4];
    __shared__ alignas(16) float zs[CH * Mg];                 // 25.6 KB
    __shared__ alignas(16) unsigned long long ypk[CH * Kk];   // 6.4 KB

    const int tid = threadIdx.x;
    const bool own = (tid < Mg);
    const int b = Nc * tid;

    float u0=0.f,u1=0.f,u2=0.f,u3=0.f,u4=0.f,u5=0.f;
    float p0=0.f,p1=0.f,p2=0.f,p3=0.f,p4=0.f,p5=0.f;
    float b0=0.f,b1=0.f,b2=0.f,b3=0.f,b4=0.f,b5=0.f;
    float alpha = 0.f;
    if (own) {
        b0=bb[b]; b1=bb[b+1]; b2=bb[b+2]; b3=bb[b+3]; b4=bb[b+4]; b5=bb[b+5];
    }
    // prologue: stage chunk 0 of Za
    #pragma unroll
    for (int i = 0; i < 7; ++i) {
        int idx = i * 1024 + tid * 4;
        if (idx < CH * Mg) {
            float4 v = *reinterpret_cast<const float4*>(Za + idx);
            *reinterpret_cast<float4*>(zs + idx) = v;
        }
    }
    __syncthreads();

    const float* baseW = WbT + b;

    for (int t = 0; t < Tn; ++t) {
        const int tc = t & (CH - 1);

        // ---- A: sigma from registers + staged za, wave-min -> red
        float s0=0,s1=0,s2=0,s3=0,s4=0,s5=0;
        float lmin = INFINITY;
        if (own) {
            float zbv = zs[tc * Mg + tid];
            float inv = (alpha == 0.f) ? 1.f : (1.f / alpha);
            s0 = fmaf(u0, inv, b0 + zbv); s1 = fmaf(u1, inv, b1 + zbv);
            s2 = fmaf(u2, inv, b2 + zbv); s3 = fmaf(u3, inv, b3 + zbv);
            s4 = fmaf(u4, inv, b4 + zbv); s5 = fmaf(u5, inv, b5 + zbv);
            lmin = fminf(fminf(fminf(s0,s1),fminf(s2,s3)),fminf(s4,s5));
        }
        for (int o = 32; o; o >>= 1) lmin = fminf(lmin, __shfl_down(lmin, o));
        if ((tid & 63) == 0) red[tid >> 6] = lmin;
        __syncthreads();                                   // bar1

        // ---- B: global min, pi, per-group argmax, sortable key
        unsigned long long myk = 0ull;
        float sb=0.f, pb=0.f; int bj = 0;
        if (own) {
            float4 r4 = *reinterpret_cast<const float4*>(red);
            float m1 = 1.f - fminf(fminf(r4.x, r4.y), fminf(r4.z, r4.w));
            float best = -INFINITY;
            float sa[6] = {s0,s1,s2,s3,s4,s5};
            float pa[6] = {p0,p1,p2,p3,p4,p5};
            #pragma unroll
            for (int j = 0; j < Nc; ++j) {
                float pv = (1.f - pa[j]) * (sa[j] + m1);
                if (pv > best) { best = pv; bj = j; sb = sa[j]; pb = pa[j]; }
            }
            unsigned ub = __float_as_uint(best);
            ub ^= (unsigned)(((int)ub) >> 31) | 0x80000000u;
            myk = ((unsigned long long)ub << 32) | (unsigned long long)(0xFFFFFFFFu - (unsigned)tid);
            lamk[tid] = myk;
        }
        __syncthreads();                                   // bar2

        // ---- C: rank scan (uniform-address broadcast reads), select, psi
        if (own) {
            float y  = tanhf(sb);                          // overlaps scan
            float yv = fmaxf(y, 0.f);
            float dc = fmaxf(y - 0.5f * pb, 0.f);
            int r = 0;
            const ulonglong2* L = reinterpret_cast<const ulonglong2*>(lamk);
            #pragma unroll
            for (int qq = 0; qq < Mg / 2; ++qq) {
                ulonglong2 kv = L[qq];
                r += (kv.x > myk) + (kv.y > myk);
            }
            float d = 0.f;
            if (r < Kk) {
                d = dc;
                sel[r] = ((unsigned long long)(unsigned)((b + bj) * TOT) << 32) |
                         (unsigned long long)__float_as_uint(d);
                ypk[tc * Kk + r] = ((unsigned long long)(unsigned)tid << 32) |
                                   (unsigned long long)__float_as_uint(yv);
            }
            p0 = 0.5f*p0 + ((bj==0)?d:0.f); p1 = 0.5f*p1 + ((bj==1)?d:0.f);
            p2 = 0.5f*p2 + ((bj==2)?d:0.f); p3 = 0.5f*p3 + ((bj==3)?d:0.f);
            p4 = 0.5f*p4 + ((bj==4)?d:0.f); p5 = 0.5f*p5 + ((bj==5)?d:0.f);
        }
        __syncthreads();                                   // bar3

        // ---- E: sel decode, all-columns gather, u update, alpha
        if (own) {
            ulonglong2 sraw[13];
            const ulonglong2* S = reinterpret_cast<const ulonglong2*>(sel);
            #pragma unroll
            for (int qq = 0; qq < 13; ++qq) sraw[qq] = S[qq];
            float sd[Kk]; int so[Kk];
            #pragma unroll
            for (int k = 0; k < Kk; ++k) {
                unsigned long long v = (k & 1) ? sraw[k >> 1].y : sraw[k >> 1].x;
                sd[k] = __uint_as_float((unsigned)v);
                so[k] = (int)(v >> 32);
            }
            float asum = 0.f;
            #pragma unroll
            for (int k = 0; k < Kk; ++k) asum += sd[k];
            alpha = 0.5f * alpha + asum;

            float2 c0[Kk], c1[Kk], c2[Kk];
            #pragma unroll
            for (int k = 0; k < Kk; ++k) {
                const float* cp = baseW + so[k];
                c0[k] = *reinterpret_cast<const float2*>(cp);
                c1[k] = *reinterpret_cast<const float2*>(cp + 2);
                c2[k] = *reinterpret_cast<const float2*>(cp + 4);
            }
            __builtin_amdgcn_sched_barrier(0);             // cluster loads before FMAs
            float a0=0.5f*u0, a1=0.5f*u1, a2=0.5f*u2, a3=0.5f*u3, a4=0.5f*u4, a5=0.5f*u5;
            #pragma unroll
            for (int k = 0; k < Kk; ++k) {
                float dk = sd[k];
                a0 = fmaf(dk, c0[k].x, a0); a1 = fmaf(dk, c0[k].y, a1);
                a2 = fmaf(dk, c1[k].x, a2); a3 = fmaf(dk, c1[k].y, a3);
                a4 = fmaf(dk, c2[k].x, a4); a5 = fmaf(dk, c2[k].y, a5);
            }
            u0=a0; u1=a1; u2=a2; u3=a3; u4=a4; u5=a5;
        }

        // ---- chunk boundary: flush Y, stage next Za chunk (all 256 threads)
        if (tc == CH - 1) {
            const size_t t0 = (size_t)(t - (CH - 1)) * Kk;
            for (int i = tid; i < CH * Kk; i += 256)
                YP[t0 + i] = ypk[i];
            if (t + 1 < Tn) {
                const float* src = Za + (size_t)(t + 1) * Mg;
                #pragma unroll
                for (int i = 0; i < 7; ++i) {
                    int idx = i * 1024 + tid * 4;
                    if (idx < CH * Mg) {
                        float4 v = *reinterpret_cast<const float4*>(src + idx);
                        *reinterpret_cast<float4*>(zs + idx) = v;
                    }
                }
            }
            __syncthreads();                               // guards zs overwrite
        }
    }

    // ---- epilogue: x_b, phi, psi
    if (own) {
        float inv = (alpha == 0.f) ? 1.f : (1.f / alpha);
        float pa[6] = {p0,p1,p2,p3,p4,p5};
        #pragma unroll
        for (int j = 0; j < Nc; ++j) {
            outTail[b + j]           = pa[j] * inv;
            outTail[TOT + b + j]     = pa[j];
            outTail[2 * TOT + b + j] = pa[j];
        }
    }
}

// ------------------------------------------------- preds = bd + sum val * WdT[idx]
__global__ void preds_k(const unsigned long long* __restrict__ YP,
                        const float* __restrict__ WdT, const float* __restrict__ bd,
                        float* __restrict__ out) {
    const int t = blockIdx.x;
    __shared__ float sv[Kk];
    __shared__ int   si[Kk];
    if (threadIdx.x < Kk) {
        unsigned long long v = YP[(size_t)t * Kk + threadIdx.x];
        sv[threadIdx.x] = __uint_as_float((unsigned)v);
        si[threadIdx.x] = (int)(v >> 32);
    }
    __syncthreads();
    for (int d = threadIdx.x; d < Din; d += 256) {
        float acc = bd[d];
        #pragma unroll
        for (int k = 0; k < Kk; ++k)
            acc = fmaf(sv[k], WdT[(size_t)si[k] * Din + d], acc);
        out[(size_t)t * Din + d] = acc;
    }
}

extern "C" void kernel_launch(void* const* d_in, const int* in_sizes, int n_in,
                              void* d_out, int out_size, void* d_ws, size_t ws_size,
                              hipStream_t stream) {
    const float* X  = (const float*)d_in[0];
    const float* Wa = (const float*)d_in[1];
    const float* ba = (const float*)d_in[2];
    const float* Wb = (const float*)d_in[3];
    const float* bb = (const float*)d_in[4];
    const float* Wd = (const float*)d_in[5];
    const float* bd = (const float*)d_in[6];
    float* out = (float*)d_out;

    float* w    = (float*)d_ws;
    float* Za   = w;                                    // 16384*200
    float* WbT  = Za  + (size_t)Tn * Mg;                // 1200*1200
    float* WdT  = WbT + (size_t)TOT * TOT;              // 200*784
    unsigned long long* YP =
        (unsigned long long*)(WdT + (size_t)Mg * Din);  // 16384*25 u64

    dim3 tb(32, 8);
    transpose_k<<<dim3((TOT + 31) / 32, (TOT + 31) / 32), tb, 0, stream>>>(Wb, WbT, TOT, TOT);
    transpose_k<<<dim3((Mg + 31) / 32, (Din + 31) / 32), tb, 0, stream>>>(Wd, WdT, Din, Mg);
    za_k<<<Tn / 16, 256, 0, stream>>>(X, Wa, ba, Za);
    serial_k<<<1, 256, 0, stream>>>(Za, WbT, bb, YP, out + (size_t)Tn * Din);
    preds_k<<<Tn, 256, 0, stream>>>(YP, WdT, bd, out);
}